// Round 11
// baseline (543.788 us; speedup 1.0000x reference)
//
#include <hip/hip_runtime.h>
#include <stdint.h>

#define NQ 12
#define NIT 15
#define AMPS 32
#define CPB (NIT * NQ)   // 180 fused gate matrices

// One 128-thread block (2 waves) per batch element, 32 amps/lane.
// Physical coords: (wv:1, lane:6, r:5).
// Layout A: amp bit 11 <- wv ; bits 10..5 <- lane5..0 ; bits 4..0 <- r4..0
// Layout B: amp bit 11 <- r4 ; bits 10..5 <- lane5..0 ; bit 4 <- wv ; bits 3..0 <- r3..0
// Wire w acts on amp bit (11-w):
//   wire0/wire7 -> bits 11/4: alternate wv <-> r4 via a pairwise bit-transpose
//     (swap contents of amp bits 11 and 4): each thread swaps its 16 "other
//     half" amps (r4 != wv) with the partner thread in the other wave.
//   wires 1..6 -> lane bits 5..0 -> permlane32/16_swap, DPP ror8, ds_swizzle,
//     DPP quad_perms (xor 32,16,8,4,2,1)
//   wires 8..11 -> r3..r0 -> register butterflies (strides 8,4,2,1)
// Per iteration: pre-gates {wire7|wire0 (stride16), 8..11, lane 1..6},
// transpose, post-gate {wire0|wire7}, CZ (mask per resulting layout).
// it0 = product-state fast path directly in layout B.
// 2-wave barriers + ~8 blocks/CU (19.5 KB LDS) hide sync/DS stalls that
// bounded the 4-wave R10 structure. All state indices compile-time (no
// scratch). Plain one-arg __launch_bounds__ only (R3/R4: min-waves hints
// mis-lower -> VGPR 64 -> state spills).

typedef float f2 __attribute__((ext_vector_type(2)));

static __device__ __forceinline__ float f_u(unsigned u) { return __uint_as_float(u); }
static __device__ __forceinline__ unsigned u_f(float f) { return __float_as_uint(f); }

// ---- packed complex primitives ----
#define PK_MUL_RR(acc, C, S) \
    asm("v_pk_mul_f32 %0, %1, %2 op_sel_hi:[0,1]" : "=v"(acc) : "v"(C), "v"(S))
#define PK_FMA_I(acc, C, S) \
    asm("v_pk_fma_f32 %0, %1, %2, %0 op_sel:[1,1,0] op_sel_hi:[1,0,1] neg_lo:[1,0,0]" \
        : "+v"(acc) : "v"(C), "v"(S))
#define PK_FMA_R(acc, C, S) \
    asm("v_pk_fma_f32 %0, %1, %2, %0 op_sel_hi:[0,1,1]" : "+v"(acc) : "v"(C), "v"(S))
#define PK_FMA_IC(acc, C, S) \
    asm("v_pk_fma_f32 %0, %1, %2, %0 op_sel:[1,1,0] op_sel_hi:[1,0,1] neg_hi:[1,0,0]" \
        : "+v"(acc) : "v"(C), "v"(S))
#define PK_FMA_RN(acc, C, S) \
    asm("v_pk_fma_f32 %0, %1, %2, %0 op_sel_hi:[0,1,1] neg_lo:[1,0,0] neg_hi:[1,0,0]" \
        : "+v"(acc) : "v"(C), "v"(S))

// DST = CA (x) CB  (complex product)
#define CMUL(DST, CA, CB) \
    { PK_MUL_RR(DST, CA, CB); PK_FMA_I(DST, CA, CB); }

// DST = CA (.) S + CB (.) O
#define CPLX_AB(DST, CA, S, CB, O)                                    \
    { f2 t_;                                                          \
      PK_MUL_RR(t_, CA, S); PK_FMA_I(t_, CA, S);                      \
      PK_FMA_R (t_, CB, O); PK_FMA_I(t_, CB, O);                      \
      DST = t_; }

template <int CTRL>
static __device__ __forceinline__ float dpp_xor(float v) {
    int u = (int)__float_as_uint(v);
    return __uint_as_float((unsigned)__builtin_amdgcn_update_dpp(u, u, CTRL, 0xF, 0xF, false));
}
static __device__ __forceinline__ float swz_xor4(float v) {
    return f_u((unsigned)__builtin_amdgcn_ds_swizzle((int)u_f(v), 0x101F));
}

#define AB_GATE_PK(OPX)                                                 \
    _Pragma("unroll")                                                   \
    for (int r = 0; r < AMPS; ++r) {                                    \
        f2 o; o.x = OPX(s[r].x); o.y = OPX(s[r].y);                     \
        CPLX_AB(s[r], CA, s[r], CB, o)                                  \
    }

// Register-bit wire: s0' = a(.)s0 + b(.)s1 ; s1' = -conj(b)(.)s0 + conj(a)(.)s1
template <int ST>
static __device__ __forceinline__ void reg_gate_pk(f2 (&s)[AMPS], f2 CAg, f2 CBg) {
#pragma unroll
    for (int r0 = 0; r0 < AMPS; ++r0) {
        if (r0 & ST) continue;
        const int r1 = r0 | ST;
        const f2 s0 = s[r0], s1 = s[r1];
        f2 t0, t1;
        PK_MUL_RR(t0, CAg, s0); PK_FMA_I (t0, CAg, s0);
        PK_FMA_R (t0, CBg, s1); PK_FMA_I (t0, CBg, s1);
        PK_MUL_RR(t1, CAg, s1); PK_FMA_IC(t1, CAg, s1);
        PK_FMA_RN(t1, CBg, s0); PK_FMA_I (t1, CBg, s0);
        s[r0] = t0; s[r1] = t1;
    }
}

// ---- fused U = RZ*RY*RX coefficient math ----
static __device__ __forceinline__ float4 build_coef(float alpha, float beta, float gamma) {
    float sa, ca, sb, cb, sg, cg;
    sincosf(0.5f * alpha, &sa, &ca);
    sincosf(0.5f * beta,  &sb, &cb);
    sincosf(0.5f * gamma, &sg, &cg);
    float cbca = cb * ca, sbsa = sb * sa, sbca = sb * ca, cbsa = cb * sa;
    float ar =  cg * cbca + sg * sbsa;
    float ai =  cg * sbsa - sg * cbca;
    float br = -(cg * sbca + sg * cbsa);
    float bi =  sg * sbca - cg * cbsa;
    return make_float4(ar, ai, br, bi);
}

// column-0 entry of U for a given wire bit: bit ? (-br, bi) : (ar, ai)
static __device__ __forceinline__ f2 usel(float4 c, int bit) {
    return bit ? f2{ -c.z, c.w } : f2{ c.x, c.y };
}

__global__ __launch_bounds__(128) void qsim_kernel(
    const float* __restrict__ x,
    const float* __restrict__ iscale,
    const float* __restrict__ w,
    const float* __restrict__ oscale,
    float* __restrict__ out)
{
    const int tid  = threadIdx.x;
    const int lane = tid & 63;
    const int wv   = tid >> 6;
    const int b    = blockIdx.x;

    __shared__ float4 buf[8 * 128];   // 16 KB transpose buffer
    __shared__ float4 clds[CPB];      // 2.88 KB coef table

    // ---- prologue: 180 fused gate matrices into LDS ----
    for (int t = tid; t < CPB; t += 128) {
        const int it  = t / NQ;
        const int q   = t - it * NQ;
        const int blk = it - 3 * (it / 3);
        float f     = x[(size_t)b * (4 * NQ) + NQ + blk * NQ + q];
        float alpha = iscale[it * NQ + q] * f;
        clds[t] = build_coef(alpha, w[it * 2 * NQ + q], w[it * 2 * NQ + NQ + q]);
    }

    // ---- CZ-ring sign masks for both layouts ----
    unsigned czmA = 0, czmB = 0;
#pragma unroll
    for (int r = 0; r < AMPS; ++r) {
        unsigned ia = ((unsigned)wv << 11) | ((unsigned)lane << 5) | (unsigned)r;
        unsigned ib = (((unsigned)r >> 4) << 11) | ((unsigned)lane << 5)
                    | ((unsigned)wv << 4) | ((unsigned)r & 15u);
        unsigned pa = ((unsigned)__popc((ia & (ia >> 1)) & 0x7FFu) + ((ia & (ia >> 11)) & 1u)) & 1u;
        unsigned pb = ((unsigned)__popc((ib & (ib >> 1)) & 0x7FFu) + ((ib & (ib >> 11)) & 1u)) & 1u;
        czmA |= pa << r;
        czmB |= pb << r;
    }

    // lane-wire constants (wires 1..6 <-> lane bits 5..0 in both layouts)
    const bool hbW1 = (lane >> 5) & 1;                       // wire1: xor32
    const bool hbW2 = (lane >> 4) & 1;                       // wire2: xor16
    const unsigned sbW3 = (unsigned)((lane >> 3) & 1) << 31; // wire3: xor8
    const unsigned sbW4 = (unsigned)((lane >> 2) & 1) << 31; // wire4: xor4
    const unsigned sbW5 = (unsigned)((lane >> 1) & 1) << 31; // wire5: xor2
    const unsigned sbW6 = (unsigned)(lane & 1) << 31;        // wire6: xor1

    __syncthreads();   // coef table ready

    f2 s[AMPS];

    // ========== it0: product-state fast path, built in layout B ==========
    // amp(idx) = prod_q U_q[bit_q, 0]; layout B bits: 11=r4, 10..5=lane, 4=wv, 3..0=r.
    {
        float4 c0 = clds[0], c1 = clds[1], c2 = clds[2],  c3 = clds[3];
        float4 c4 = clds[4], c5 = clds[5], c6 = clds[6],  c7 = clds[7];
        float4 c8 = clds[8], c9 = clds[9], cA = clds[10], cB = clds[11];

        f2 tc = usel(c1, (lane >> 5) & 1);
        { f2 u = usel(c2, (lane >> 4) & 1); f2 t; CMUL(t, tc, u) tc = t; }
        { f2 u = usel(c3, (lane >> 3) & 1); f2 t; CMUL(t, tc, u) tc = t; }
        { f2 u = usel(c4, (lane >> 2) & 1); f2 t; CMUL(t, tc, u) tc = t; }
        { f2 u = usel(c5, (lane >> 1) & 1); f2 t; CMUL(t, tc, u) tc = t; }
        { f2 u = usel(c6, lane & 1);        f2 t; CMUL(t, tc, u) tc = t; }
        { f2 u = usel(c7, wv);              f2 t; CMUL(t, tc, u) tc = t; }
        f2 tc0, tc1;
        { f2 u = usel(c0, 0); CMUL(tc0, tc, u) }
        { f2 u = usel(c0, 1); CMUL(tc1, tc, u) }

        f2 pA[4], pB[4], plow[16];
#pragma unroll
        for (int j = 0; j < 4; ++j) {
            f2 u8 = usel(c8, j >> 1), u9 = usel(c9, j & 1);
            CMUL(pA[j], u8, u9)
            f2 uA = usel(cA, j >> 1), uB = usel(cB, j & 1);
            CMUL(pB[j], uA, uB)
        }
#pragma unroll
        for (int m = 0; m < 16; ++m) CMUL(plow[m], pA[m >> 2], pB[m & 3])
#pragma unroll
        for (int r = 0; r < AMPS; ++r) CMUL(s[r], (r < 16 ? tc0 : tc1), plow[r & 15])

        // CZ in layout B
#pragma unroll
        for (int r = 0; r < AMPS; ++r) {
            const unsigned sgn = ((czmB >> r) & 1u) << 31;
            s[r].x = f_u(u_f(s[r].x) ^ sgn);
            s[r].y = f_u(u_f(s[r].y) ^ sgn);
        }
    }

    // ========== iterations 1..14 ==========
#pragma unroll 1
    for (int it = 1; it < NIT; ++it) {
        const float4* cit = clds + it * NQ;
        const bool ev = (it & 1) == 0;   // even iters enter layout A

        // ---- pre-transpose register wires ----
        // entering A: r4 holds wire7; entering B: r4 holds wire0. r3..r0 = wires 8..11.
        { float4 cf = cit[ev ? 7 : 0];
          const f2 CA = { cf.x, cf.y }, CB = { cf.z, cf.w }; reg_gate_pk<16>(s, CA, CB); }
        { float4 cc = cit[8];
          const f2 CA = { cc.x, cc.y }, CB = { cc.z, cc.w }; reg_gate_pk<8>(s, CA, CB); }
        { float4 cc = cit[9];
          const f2 CA = { cc.x, cc.y }, CB = { cc.z, cc.w }; reg_gate_pk<4>(s, CA, CB); }
        { float4 cc = cit[10];
          const f2 CA = { cc.x, cc.y }, CB = { cc.z, cc.w }; reg_gate_pk<2>(s, CA, CB); }
        { float4 cc = cit[11];
          const f2 CA = { cc.x, cc.y }, CB = { cc.z, cc.w }; reg_gate_pk<1>(s, CA, CB); }

        // ---- lane wires (1..6) ----
        { // wire1: xor32 -> permlane32_swap
            float4 cc = cit[1];
            const f2 CP = { hbW1 ? -cc.z : cc.x, hbW1 ?  cc.w : cc.y };
            const f2 CQ = { hbW1 ?  cc.x : cc.z, hbW1 ? -cc.y : cc.w };
#pragma unroll
            for (int r = 0; r < AMPS; ++r) {
                auto dx = __builtin_amdgcn_permlane32_swap(u_f(s[r].x), u_f(s[r].x), false, false);
                auto dy = __builtin_amdgcn_permlane32_swap(u_f(s[r].y), u_f(s[r].y), false, false);
                f2 na = { f_u(dx[0]), f_u(dy[0]) };
                f2 nb = { f_u(dx[1]), f_u(dy[1]) };
                CPLX_AB(s[r], CP, na, CQ, nb)
            }
        }
        { // wire2: xor16 -> permlane16_swap
            float4 cc = cit[2];
            const f2 CP = { hbW2 ? -cc.z : cc.x, hbW2 ?  cc.w : cc.y };
            const f2 CQ = { hbW2 ?  cc.x : cc.z, hbW2 ? -cc.y : cc.w };
#pragma unroll
            for (int r = 0; r < AMPS; ++r) {
                auto dx = __builtin_amdgcn_permlane16_swap(u_f(s[r].x), u_f(s[r].x), false, false);
                auto dy = __builtin_amdgcn_permlane16_swap(u_f(s[r].y), u_f(s[r].y), false, false);
                f2 na = { f_u(dx[0]), f_u(dy[0]) };
                f2 nb = { f_u(dx[1]), f_u(dy[1]) };
                CPLX_AB(s[r], CP, na, CQ, nb)
            }
        }
        { // wire3: xor8 -> DPP row_ror:8
            float4 cc = cit[3];
            const f2 CA = { cc.x, f_u(u_f(cc.y) ^ sbW3) };
            const f2 CB = { f_u(u_f(cc.z) ^ sbW3), cc.w };
            AB_GATE_PK(dpp_xor<0x128>)
        }
        { // wire4: xor4 -> ds_swizzle, chunks of 8 amps to bound temps
            float4 cc = cit[4];
            const f2 CA = { cc.x, f_u(u_f(cc.y) ^ sbW4) };
            const f2 CB = { f_u(u_f(cc.z) ^ sbW4), cc.w };
#pragma unroll
            for (int h = 0; h < 4; ++h) {
                float ox[8], oy[8];
#pragma unroll
                for (int r = 0; r < 8; ++r) {
                    ox[r] = swz_xor4(s[h*8 + r].x);
                    oy[r] = swz_xor4(s[h*8 + r].y);
                }
#pragma unroll
                for (int r = 0; r < 8; ++r) {
                    f2 o = { ox[r], oy[r] };
                    CPLX_AB(s[h*8 + r], CA, s[h*8 + r], CB, o)
                }
            }
        }
        { // wire5: xor2 -> DPP quad_perm [2,3,0,1]
            float4 cc = cit[5];
            const f2 CA = { cc.x, f_u(u_f(cc.y) ^ sbW5) };
            const f2 CB = { f_u(u_f(cc.z) ^ sbW5), cc.w };
            AB_GATE_PK(dpp_xor<0x4E>)
        }
        { // wire6: xor1 -> DPP quad_perm [1,0,3,2]
            float4 cc = cit[6];
            const f2 CA = { cc.x, f_u(u_f(cc.y) ^ sbW6) };
            const f2 CB = { f_u(u_f(cc.z) ^ sbW6), cc.w };
            AB_GATE_PK(dpp_xor<0xB1>)
        }

        // ---- bit-transpose (amp bits 11 <-> 4): swap the r4 != wv half ----
        // with the partner thread (other wave, same lane). Literal indices only.
        __syncthreads();   // prior buf readers done
        if (wv == 0) {
#pragma unroll
            for (int k = 0; k < 8; ++k)
                buf[(k << 7) + tid] = make_float4(s[16+2*k].x, s[16+2*k].y,
                                                  s[17+2*k].x, s[17+2*k].y);
        } else {
#pragma unroll
            for (int k = 0; k < 8; ++k)
                buf[(k << 7) + tid] = make_float4(s[2*k].x, s[2*k].y,
                                                  s[2*k+1].x, s[2*k+1].y);
        }
        __syncthreads();
        {
            const int ptid = tid ^ 64;
            if (wv == 0) {
#pragma unroll
                for (int k = 0; k < 8; ++k) {
                    float4 v = buf[(k << 7) + ptid];
                    s[16+2*k] = f2{ v.x, v.y }; s[17+2*k] = f2{ v.z, v.w };
                }
            } else {
#pragma unroll
                for (int k = 0; k < 8; ++k) {
                    float4 v = buf[(k << 7) + ptid];
                    s[2*k] = f2{ v.x, v.y }; s[2*k+1] = f2{ v.z, v.w };
                }
            }
        }

        // ---- post-transpose register wire (the swapped-in wv wire) ----
        { float4 cl = cit[ev ? 0 : 7];
          const f2 CA = { cl.x, cl.y }, CB = { cl.z, cl.w }; reg_gate_pk<16>(s, CA, CB); }

        // ---- CZ ring, mask per resulting layout (ev: ends B, !ev: ends A) ----
        const unsigned mcz = ev ? czmB : czmA;
#pragma unroll
        for (int r = 0; r < AMPS; ++r) {
            const unsigned sgn = ((mcz >> r) & 1u) << 31;
            s[r].x = f_u(u_f(s[r].x) ^ sgn);
            s[r].y = f_u(u_f(s[r].y) ^ sgn);
        }
    }

    // ---- expvals. Final layout: B (it14 even: enters A, ends B).
    // wire0 = amp bit 11 = r4; wire1 = bit10 = lane5; wire2 = bit9 = lane4;
    // wire3 = bit8 = lane3.
    float plo = 0.f, phi = 0.f;
#pragma unroll
    for (int r = 0; r < 16; ++r) plo = fmaf(s[r].x, s[r].x, fmaf(s[r].y, s[r].y, plo));
#pragma unroll
    for (int r = 16; r < 32; ++r) phi = fmaf(s[r].x, s[r].x, fmaf(s[r].y, s[r].y, phi));

    const float ptot = plo + phi;
    float v0 = plo - phi;                            // sign by r4
    float v1 = hbW1 ? -ptot : ptot;                  // lane5
    float v2 = hbW2 ? -ptot : ptot;                  // lane4
    float v3 = ((lane >> 3) & 1) ? -ptot : ptot;     // lane3
#pragma unroll
    for (int m = 1; m <= 32; m <<= 1) {
        v0 += __shfl_xor(v0, m);
        v1 += __shfl_xor(v1, m);
        v2 += __shfl_xor(v2, m);
        v3 += __shfl_xor(v3, m);
    }

    __syncthreads();   // buf reuse for cross-wave reduction
    if (lane == 0) buf[wv] = make_float4(v0, v1, v2, v3);
    __syncthreads();
    if (tid == 0) {
        float4 a0 = buf[0], a1 = buf[1];
        float4 o;
        o.x = (a0.x + a1.x) * oscale[0];
        o.y = (a0.y + a1.y) * oscale[1];
        o.z = (a0.z + a1.z) * oscale[2];
        o.w = (a0.w + a1.w) * oscale[3];
        *reinterpret_cast<float4*>(out + (size_t)b * 4) = o;
    }
}

extern "C" void kernel_launch(void* const* d_in, const int* in_sizes, int n_in,
                              void* d_out, int out_size, void* d_ws, size_t ws_size,
                              hipStream_t stream) {
    const float* x      = (const float*)d_in[0];
    const float* iscale = (const float*)d_in[1];
    const float* w      = (const float*)d_in[2];
    const float* oscale = (const float*)d_in[3];
    float* out          = (float*)d_out;

    const int batch = in_sizes[0] / (4 * NQ);
    qsim_kernel<<<batch, 128, 0, stream>>>(x, iscale, w, oscale, out);
}

// Round 12
// 520.784 us; speedup vs baseline: 1.0442x; 1.0442x over previous
//
#include <hip/hip_runtime.h>
#include <stdint.h>

#define NQ 12
#define NIT 15
#define AMPS 16
#define CPB (NIT * NQ)   // 180 fused gate matrices per batch element

// One 256-thread block (4 waves) per batch element, 16 amps/lane (R10 best).
// Layout A: idx bits  b11,b10 = wv ; b9..b4 = lane ; b3..b0 = r
// Layout B: idx bits  b11,b10 = r3,r2 ; b9..b4 = lane ; b3,b2 = wv ; b1,b0 = r1,r0
// Bit-transpose (swap contents of bits 11,10 <-> 3,2) toggles A<->B each
// iteration; wv wires are applied as REGISTER butterflies in the layout where
// they are register bits (wires 10,11 are r-bits in BOTH layouts).
// Coefs: per-batch 180-entry table in GLOBAL memory, written by coef_kernel
// with the SAME grid shape (one block per batch) so writer and reader land on
// the same XCD -> L2-hit; block-uniform reads lower to s_load into SGPRs,
// freeing ~40 VGPRs and all per-iter DS coef traffic (R8/R9 showed the
// s_load lowering; their regression was cross-XCD cold-HBM latency).
// it0 = product-state fast path directly in layout B.
// Packed fp32 VOP3P: 4 instr/amp/gate. Plain one-arg __launch_bounds__ only
// (min-waves hints mis-lower: VGPR 64 -> state spills, R3/R4).

typedef float f2 __attribute__((ext_vector_type(2)));

static __device__ __forceinline__ float f_u(unsigned u) { return __uint_as_float(u); }
static __device__ __forceinline__ unsigned u_f(float f) { return __float_as_uint(f); }

// ---- packed complex primitives ----
#define PK_MUL_RR(acc, C, S) \
    asm("v_pk_mul_f32 %0, %1, %2 op_sel_hi:[0,1]" : "=v"(acc) : "v"(C), "v"(S))
#define PK_FMA_I(acc, C, S) \
    asm("v_pk_fma_f32 %0, %1, %2, %0 op_sel:[1,1,0] op_sel_hi:[1,0,1] neg_lo:[1,0,0]" \
        : "+v"(acc) : "v"(C), "v"(S))
#define PK_FMA_R(acc, C, S) \
    asm("v_pk_fma_f32 %0, %1, %2, %0 op_sel_hi:[0,1,1]" : "+v"(acc) : "v"(C), "v"(S))
#define PK_FMA_IC(acc, C, S) \
    asm("v_pk_fma_f32 %0, %1, %2, %0 op_sel:[1,1,0] op_sel_hi:[1,0,1] neg_hi:[1,0,0]" \
        : "+v"(acc) : "v"(C), "v"(S))
#define PK_FMA_RN(acc, C, S) \
    asm("v_pk_fma_f32 %0, %1, %2, %0 op_sel_hi:[0,1,1] neg_lo:[1,0,0] neg_hi:[1,0,0]" \
        : "+v"(acc) : "v"(C), "v"(S))

// DST = CA (x) CB  (complex product; DST must not alias CA/CB)
#define CMUL(DST, CA, CB) \
    { PK_MUL_RR(DST, CA, CB); PK_FMA_I(DST, CA, CB); }

// DST = CA (.) S + CB (.) O
#define CPLX_AB(DST, CA, S, CB, O)                                    \
    { f2 t_;                                                          \
      PK_MUL_RR(t_, CA, S); PK_FMA_I(t_, CA, S);                      \
      PK_FMA_R (t_, CB, O); PK_FMA_I(t_, CB, O);                      \
      DST = t_; }

template <int CTRL>
static __device__ __forceinline__ float dpp_xor(float v) {
    int u = (int)__float_as_uint(v);
    return __uint_as_float((unsigned)__builtin_amdgcn_update_dpp(u, u, CTRL, 0xF, 0xF, false));
}
static __device__ __forceinline__ float swz_xor4(float v) {
    return f_u((unsigned)__builtin_amdgcn_ds_swizzle((int)u_f(v), 0x101F));
}

#define AB_GATE_PK(OPX)                                                 \
    _Pragma("unroll")                                                   \
    for (int r = 0; r < AMPS; ++r) {                                    \
        f2 o; o.x = OPX(s[r].x); o.y = OPX(s[r].y);                     \
        CPLX_AB(s[r], CA, s[r], CB, o)                                  \
    }

// Register-bit wire: s0' = a(.)s0 + b(.)s1 ; s1' = -conj(b)(.)s0 + conj(a)(.)s1
template <int ST>
static __device__ __forceinline__ void reg_gate_pk(f2 (&s)[AMPS], f2 CAg, f2 CBg) {
#pragma unroll
    for (int r0 = 0; r0 < AMPS; ++r0) {
        if (r0 & ST) continue;
        const int r1 = r0 | ST;
        const f2 s0 = s[r0], s1 = s[r1];
        f2 t0, t1;
        PK_MUL_RR(t0, CAg, s0); PK_FMA_I (t0, CAg, s0);
        PK_FMA_R (t0, CBg, s1); PK_FMA_I (t0, CBg, s1);
        PK_MUL_RR(t1, CAg, s1); PK_FMA_IC(t1, CAg, s1);
        PK_FMA_RN(t1, CBg, s0); PK_FMA_I (t1, CBg, s0);
        s[r0] = t0; s[r1] = t1;
    }
}

// ---- fused U = RZ*RY*RX coefficient math ----
static __device__ __forceinline__ float4 build_coef(float alpha, float beta, float gamma) {
    float sa, ca, sb, cb, sg, cg;
    sincosf(0.5f * alpha, &sa, &ca);
    sincosf(0.5f * beta,  &sb, &cb);
    sincosf(0.5f * gamma, &sg, &cg);
    float cbca = cb * ca, sbsa = sb * sa, sbca = sb * ca, cbsa = cb * sa;
    float ar =  cg * cbca + sg * sbsa;
    float ai =  cg * sbsa - sg * cbca;
    float br = -(cg * sbca + sg * cbsa);
    float bi =  sg * sbca - cg * cbsa;
    return make_float4(ar, ai, br, bi);
}

// column-0 entry of U for a given wire bit: bit ? (-br, bi) : (ar, ai)
static __device__ __forceinline__ f2 usel(float4 c, int bit) {
    return bit ? f2{ -c.z, c.w } : f2{ c.x, c.y };
}

// One block per batch element (same grid shape as qsim_kernel -> same XCD
// under round-robin dispatch -> the 2.88 KB table is L2-local to its reader).
__global__ __launch_bounds__(256) void coef_kernel(
    const float* __restrict__ x, const float* __restrict__ iscale,
    const float* __restrict__ w, float4* __restrict__ ctab)
{
    const int b = blockIdx.x;
    const int t = threadIdx.x;
    if (t < CPB) {
        const int it  = t / NQ;
        const int q   = t - it * NQ;
        const int blk = it - 3 * (it / 3);
        float f     = x[(size_t)b * (4 * NQ) + NQ + blk * NQ + q];
        float alpha = iscale[it * NQ + q] * f;
        ctab[(size_t)b * CPB + t] =
            build_coef(alpha, w[it * 2 * NQ + q], w[it * 2 * NQ + NQ + q]);
    }
}

template <bool TAB>
__global__ __launch_bounds__(256) void qsim_kernel(
    const float* __restrict__ x,
    const float* __restrict__ iscale,
    const float* __restrict__ w,
    const float* __restrict__ oscale,
    const float4* __restrict__ ctab,
    float* __restrict__ out)
{
    const int tid  = threadIdx.x;
    const int lane = tid & 63;
    const int wv   = tid >> 6;
    const int b    = blockIdx.x;

    extern __shared__ float4 smem[];
    float4* buf  = smem;          // 24 KB transpose buffer
    float4* clds = smem + 1536;   // fallback coef table (!TAB only)

#define TBUF(SLOT, Q) buf[((((SLOT) << 1) | (Q)) << 6) | lane]

    if constexpr (!TAB) {
        if (tid < CPB) {
            const int it  = tid / NQ;
            const int q   = tid - it * NQ;
            const int blk = it - 3 * (it / 3);
            float f     = x[(size_t)b * (4 * NQ) + NQ + blk * NQ + q];
            float alpha = iscale[it * NQ + q] * f;
            clds[tid] = build_coef(alpha, w[it * 2 * NQ + q], w[it * 2 * NQ + NQ + q]);
        }
    }

    // CZ-ring sign masks for BOTH layouts
    unsigned czmA = 0, czmB = 0;
#pragma unroll
    for (int r = 0; r < AMPS; ++r) {
        unsigned ia = ((unsigned)wv << 10) | ((unsigned)lane << 4) | (unsigned)r;
        unsigned ib = (((unsigned)(r >> 3) & 1u) << 11) | (((unsigned)(r >> 2) & 1u) << 10)
                    | ((unsigned)lane << 4)
                    | (((unsigned)(wv >> 1) & 1u) << 3) | (((unsigned)wv & 1u) << 2)
                    | ((unsigned)r & 3u);
        unsigned pa = ((unsigned)__popc((ia & (ia >> 1)) & 0x7FFu) + ((ia & (ia >> 11)) & 1u)) & 1u;
        unsigned pb = ((unsigned)__popc((ib & (ib >> 1)) & 0x7FFu) + ((ib & (ib >> 11)) & 1u)) & 1u;
        czmA |= pa << r;
        czmB |= pb << r;
    }

    // lane-wire per-thread constants (bits 9..4 = wires 2..7 in BOTH layouts)
    const bool hb2 = (lane >> 5) & 1;
    const bool hb3 = (lane >> 4) & 1;
    const unsigned sb4 = (unsigned)((lane >> 3) & 1) << 31;
    const unsigned sb5 = (unsigned)((lane >> 2) & 1) << 31;
    const unsigned sb6 = (unsigned)((lane >> 1) & 1) << 31;
    const unsigned sb7 = (unsigned)(lane & 1) << 31;

    const float4* gtab = TAB ? (ctab + (size_t)b * CPB) : nullptr;

    if constexpr (!TAB) __syncthreads();   // coef table ready

    f2 s[AMPS];

    // ================= iteration 0: product-state fast path =================
    // amp(idx) = prod_q U_q[bit_q, 0];  U[0,0] = (ar,ai), U[1,0] = (-br, bi).
    // Built directly in layout B; CZ with czmB.
    {
        float4 c[NQ];
        if constexpr (TAB) {
#pragma unroll
            for (int q = 0; q < NQ; ++q) c[q] = gtab[q];
        } else {
#pragma unroll
            for (int q = 0; q < NQ; ++q) c[q] = clds[q];
        }

        // thread-constant product: wires 2..7 (lane bits 5..0), 8,9 (wv bits)
        f2 tc = usel(c[2], (lane >> 5) & 1);
#pragma unroll
        for (int wq = 3; wq <= 7; ++wq) {
            const f2 uw = usel(c[wq], (lane >> (7 - wq)) & 1);
            f2 t; CMUL(t, tc, uw) tc = t;
        }
        { f2 u = usel(c[8], (wv >> 1) & 1); f2 t; CMUL(t, tc, u) tc = t; }
        { f2 u = usel(c[9], wv & 1);        f2 t; CMUL(t, tc, u) tc = t; }

        // ph[j]: wires 0,1 by j=r>>2 (r3 -> wire0, r2 -> wire1), tc folded in
        // pl[k]: wires 10,11 by k=r&3 (r1 -> wire10, r0 -> wire11)
        f2 ph[4], pl[4];
#pragma unroll
        for (int j = 0; j < 4; ++j) {
            f2 u0 = usel(c[0], j >> 1), u1 = usel(c[1], j & 1);
            CMUL(ph[j], u0, u1)
            f2 t; CMUL(t, tc, ph[j]) ph[j] = t;
            f2 uA = usel(c[10], j >> 1), uB = usel(c[11], j & 1);
            CMUL(pl[j], uA, uB)
        }
#pragma unroll
        for (int r = 0; r < AMPS; ++r) CMUL(s[r], ph[r >> 2], pl[r & 3])

        // CZ ring in layout B
#pragma unroll
        for (int r = 0; r < AMPS; ++r) {
            const unsigned sgn = ((czmB >> r) & 1u) << 31;
            s[r].x = f_u(u_f(s[r].x) ^ sgn);
            s[r].y = f_u(u_f(s[r].y) ^ sgn);
        }
    }

    // ================= iterations 1..14 =================
#pragma unroll 2
    for (int it = 1; it < NIT; ++it) {
        float4 c[NQ];
        if constexpr (TAB) {
#pragma unroll
            for (int q = 0; q < NQ; ++q) c[q] = gtab[it * NQ + q];
        } else {
#pragma unroll
            for (int q = 0; q < NQ; ++q) c[q] = clds[it * NQ + q];
        }
        const bool ev = (it & 1) == 0;   // even iters enter layout A

        // ---- pre-transpose register wires ----
        // even (layout A): r3,r2 = wires 8,9 ; odd (layout B): r3,r2 = wires 0,1
        // wires 10,11 are r1,r0 in BOTH layouts
        {
            const float4 c0 = ev ? c[8] : c[0];
            const float4 c1 = ev ? c[9] : c[1];
            { const f2 CA = { c0.x, c0.y }, CB = { c0.z, c0.w }; reg_gate_pk<8>(s, CA, CB); }
            { const f2 CA = { c1.x, c1.y }, CB = { c1.z, c1.w }; reg_gate_pk<4>(s, CA, CB); }
            { const f2 CA = { c[10].x, c[10].y }, CB = { c[10].z, c[10].w }; reg_gate_pk<2>(s, CA, CB); }
            { const f2 CA = { c[11].x, c[11].y }, CB = { c[11].z, c[11].w }; reg_gate_pk<1>(s, CA, CB); }
        }

        // ---- lane wires (qubits 2..7), identical in both layouts ----
        { // qubit 2: xor32 -> permlane32_swap
            const f2 CP = { hb2 ? -c[2].z : c[2].x, hb2 ?  c[2].w : c[2].y };
            const f2 CQ = { hb2 ?  c[2].x : c[2].z, hb2 ? -c[2].y : c[2].w };
#pragma unroll
            for (int r = 0; r < AMPS; ++r) {
                auto dx = __builtin_amdgcn_permlane32_swap(u_f(s[r].x), u_f(s[r].x), false, false);
                auto dy = __builtin_amdgcn_permlane32_swap(u_f(s[r].y), u_f(s[r].y), false, false);
                f2 na = { f_u(dx[0]), f_u(dy[0]) };
                f2 nb = { f_u(dx[1]), f_u(dy[1]) };
                CPLX_AB(s[r], CP, na, CQ, nb)
            }
        }
        { // qubit 3: xor16 -> permlane16_swap
            const f2 CP = { hb3 ? -c[3].z : c[3].x, hb3 ?  c[3].w : c[3].y };
            const f2 CQ = { hb3 ?  c[3].x : c[3].z, hb3 ? -c[3].y : c[3].w };
#pragma unroll
            for (int r = 0; r < AMPS; ++r) {
                auto dx = __builtin_amdgcn_permlane16_swap(u_f(s[r].x), u_f(s[r].x), false, false);
                auto dy = __builtin_amdgcn_permlane16_swap(u_f(s[r].y), u_f(s[r].y), false, false);
                f2 na = { f_u(dx[0]), f_u(dy[0]) };
                f2 nb = { f_u(dx[1]), f_u(dy[1]) };
                CPLX_AB(s[r], CP, na, CQ, nb)
            }
        }
        { // qubit 4: xor8 -> DPP row_ror:8
            const f2 CA = { c[4].x, f_u(u_f(c[4].y) ^ sb4) };
            const f2 CB = { f_u(u_f(c[4].z) ^ sb4), c[4].w };
            AB_GATE_PK(dpp_xor<0x128>)
        }
        { // qubit 5: xor4 -> ds_swizzle; issue all gathers, then consume
            const f2 CA = { c[5].x, f_u(u_f(c[5].y) ^ sb5) };
            const f2 CB = { f_u(u_f(c[5].z) ^ sb5), c[5].w };
            float ox[AMPS], oy[AMPS];
#pragma unroll
            for (int r = 0; r < AMPS; ++r) {
                ox[r] = swz_xor4(s[r].x);
                oy[r] = swz_xor4(s[r].y);
            }
#pragma unroll
            for (int r = 0; r < AMPS; ++r) {
                f2 o = { ox[r], oy[r] };
                CPLX_AB(s[r], CA, s[r], CB, o)
            }
        }
        { // qubit 6: xor2 -> DPP quad_perm [2,3,0,1]
            const f2 CA = { c[6].x, f_u(u_f(c[6].y) ^ sb6) };
            const f2 CB = { f_u(u_f(c[6].z) ^ sb6), c[6].w };
            AB_GATE_PK(dpp_xor<0x4E>)
        }
        { // qubit 7: xor1 -> DPP quad_perm [1,0,3,2]
            const f2 CA = { c[7].x, f_u(u_f(c[7].y) ^ sb7) };
            const f2 CB = { f_u(u_f(c[7].z) ^ sb7), c[7].w };
            AB_GATE_PK(dpp_xor<0xB1>)
        }

        // ---- bit-transpose: swap contents of bits (11,10) <-> (3,2) ----
        __syncthreads();   // prior buf readers done
#pragma unroll
        for (int g = 0; g < 4; ++g) {
            if (g == wv) continue;                       // wave-uniform branch
            const int slot = g * 3 + (wv < g ? wv : wv - 1);
            TBUF(slot, 0) = make_float4(s[4*g+0].x, s[4*g+0].y, s[4*g+1].x, s[4*g+1].y);
            TBUF(slot, 1) = make_float4(s[4*g+2].x, s[4*g+2].y, s[4*g+3].x, s[4*g+3].y);
        }
        __syncthreads();
#pragma unroll
        for (int h = 0; h < 4; ++h) {
            if (h == wv) continue;
            const int slot = wv * 3 + (h < wv ? h : h - 1);
            const float4 pa = TBUF(slot, 0);
            const float4 pb = TBUF(slot, 1);
            s[4*h+0] = f2{ pa.x, pa.y }; s[4*h+1] = f2{ pa.z, pa.w };
            s[4*h+2] = f2{ pb.x, pb.y }; s[4*h+3] = f2{ pb.z, pb.w };
        }

        // ---- post-transpose register wires ----
        // even (now layout B): r3,r2 = wires 0,1 ; odd (now layout A): wires 8,9
        {
            const float4 c0 = ev ? c[0] : c[8];
            const float4 c1 = ev ? c[1] : c[9];
            { const f2 CA = { c0.x, c0.y }, CB = { c0.z, c0.w }; reg_gate_pk<8>(s, CA, CB); }
            { const f2 CA = { c1.x, c1.y }, CB = { c1.z, c1.w }; reg_gate_pk<4>(s, CA, CB); }
        }

        // ---- CZ ring (diagonal +-1), mask per current layout ----
        const unsigned mcz = ev ? czmB : czmA;
#pragma unroll
        for (int r = 0; r < AMPS; ++r) {
            const unsigned sgn = ((mcz >> r) & 1u) << 31;
            s[r].x = f_u(u_f(s[r].x) ^ sgn);
            s[r].y = f_u(u_f(s[r].y) ^ sgn);
        }
    }

    // ---- expvals. Final layout: B (it=14 enters A, exits B).
    // wire0 = b11 = r3, wire1 = b10 = r2, wire2 = b9 = lane5, wire3 = b8 = lane4.
    float pg[4];
#pragma unroll
    for (int g = 0; g < 4; ++g) {
        float p = 0.f;
#pragma unroll
        for (int j = 0; j < 4; ++j)
            p = fmaf(s[4*g+j].x, s[4*g+j].x, fmaf(s[4*g+j].y, s[4*g+j].y, p));
        pg[g] = p;
    }
    const float ptot = (pg[0] + pg[1]) + (pg[2] + pg[3]);
    float v0 = (pg[0] + pg[1]) - (pg[2] + pg[3]);   // sign by r3
    float v1 = (pg[0] + pg[2]) - (pg[1] + pg[3]);   // sign by r2
    float v2 = hb2 ? -ptot : ptot;                  // lane5
    float v3 = hb3 ? -ptot : ptot;                  // lane4
#pragma unroll
    for (int m = 1; m <= 32; m <<= 1) {
        v0 += __shfl_xor(v0, m);
        v1 += __shfl_xor(v1, m);
        v2 += __shfl_xor(v2, m);
        v3 += __shfl_xor(v3, m);
    }

    __syncthreads();   // buf reuse for cross-wave reduction
    if (lane == 0) buf[wv] = make_float4(v0, v1, v2, v3);
    __syncthreads();
    if (tid == 0) {
        float4 a0 = buf[0], a1 = buf[1], a2 = buf[2], a3 = buf[3];
        float4 o;
        o.x = (a0.x + a1.x + a2.x + a3.x) * oscale[0];
        o.y = (a0.y + a1.y + a2.y + a3.y) * oscale[1];
        o.z = (a0.z + a1.z + a2.z + a3.z) * oscale[2];
        o.w = (a0.w + a1.w + a2.w + a3.w) * oscale[3];
        *reinterpret_cast<float4*>(out + (size_t)b * 4) = o;
    }
#undef TBUF
}

extern "C" void kernel_launch(void* const* d_in, const int* in_sizes, int n_in,
                              void* d_out, int out_size, void* d_ws, size_t ws_size,
                              hipStream_t stream) {
    const float* x      = (const float*)d_in[0];
    const float* iscale = (const float*)d_in[1];
    const float* w      = (const float*)d_in[2];
    const float* oscale = (const float*)d_in[3];
    float* out          = (float*)d_out;

    const int batch = in_sizes[0] / (4 * NQ);
    const size_t need = (size_t)batch * CPB * sizeof(float4);

    if (ws_size >= need) {
        coef_kernel<<<batch, 256, 0, stream>>>(x, iscale, w, (float4*)d_ws);
        qsim_kernel<true><<<batch, 256, 1536 * sizeof(float4), stream>>>(
            x, iscale, w, oscale, (const float4*)d_ws, out);
    } else {
        qsim_kernel<false><<<batch, 256, (1536 + CPB) * sizeof(float4), stream>>>(
            x, iscale, w, oscale, nullptr, out);
    }
}

// Round 13
// 512.739 us; speedup vs baseline: 1.0606x; 1.0157x over previous
//
#include <hip/hip_runtime.h>
#include <stdint.h>

#define NQ 12
#define NIT 15
#define AMPS 16
#define CPB (NIT * NQ)   // 180 fused gate matrices

// One 256-thread block (4 waves) per batch element, 16 amps/lane (R10 base).
// Layout A: idx bits  b11,b10 = wv ; b9..b4 = lane ; b3..b0 = r
// Layout B: idx bits  b11,b10 = r3,r2 ; b9..b4 = lane ; b3,b2 = wv ; b1,b0 = r1,r0
// Bit-transpose (swap contents of bits 11,10 <-> 3,2) toggles A<->B each
// iteration; wv wires are applied as REGISTER butterflies in the layout where
// they are register bits (wires 10,11 are r-bits in BOTH layouts).
// Coef table in LDS (global-table variants R8/R9/R12 all regressed: cold-HBM
// fetch at each iteration head, FETCH_SIZE = full 11.6 MB table).
// it0 = product-state fast path directly in layout B.
// BARRIER PLACEMENT (this round's change): the buffer-protect barrier sits
// right AFTER the transpose reads, so the post-gates + CZ + next iteration's
// ~3000-cycle gate stretch absorbs inter-wave skew before the next writes.
// R10 had it immediately before the writes -> skew fully exposed.
// Packed fp32 VOP3P: 4 instr/amp/gate. Plain one-arg __launch_bounds__ only
// (min-waves hints mis-lower: VGPR 64 -> state spills, R3/R4).

typedef float f2 __attribute__((ext_vector_type(2)));

static __device__ __forceinline__ float f_u(unsigned u) { return __uint_as_float(u); }
static __device__ __forceinline__ unsigned u_f(float f) { return __float_as_uint(f); }

// ---- packed complex primitives ----
#define PK_MUL_RR(acc, C, S) \
    asm("v_pk_mul_f32 %0, %1, %2 op_sel_hi:[0,1]" : "=v"(acc) : "v"(C), "v"(S))
#define PK_FMA_I(acc, C, S) \
    asm("v_pk_fma_f32 %0, %1, %2, %0 op_sel:[1,1,0] op_sel_hi:[1,0,1] neg_lo:[1,0,0]" \
        : "+v"(acc) : "v"(C), "v"(S))
#define PK_FMA_R(acc, C, S) \
    asm("v_pk_fma_f32 %0, %1, %2, %0 op_sel_hi:[0,1,1]" : "+v"(acc) : "v"(C), "v"(S))
#define PK_FMA_IC(acc, C, S) \
    asm("v_pk_fma_f32 %0, %1, %2, %0 op_sel:[1,1,0] op_sel_hi:[1,0,1] neg_hi:[1,0,0]" \
        : "+v"(acc) : "v"(C), "v"(S))
#define PK_FMA_RN(acc, C, S) \
    asm("v_pk_fma_f32 %0, %1, %2, %0 op_sel_hi:[0,1,1] neg_lo:[1,0,0] neg_hi:[1,0,0]" \
        : "+v"(acc) : "v"(C), "v"(S))

// DST = CA (x) CB  (complex product; DST must not alias CA/CB)
#define CMUL(DST, CA, CB) \
    { PK_MUL_RR(DST, CA, CB); PK_FMA_I(DST, CA, CB); }

// DST = CA (.) S + CB (.) O
#define CPLX_AB(DST, CA, S, CB, O)                                    \
    { f2 t_;                                                          \
      PK_MUL_RR(t_, CA, S); PK_FMA_I(t_, CA, S);                      \
      PK_FMA_R (t_, CB, O); PK_FMA_I(t_, CB, O);                      \
      DST = t_; }

template <int CTRL>
static __device__ __forceinline__ float dpp_xor(float v) {
    int u = (int)__float_as_uint(v);
    return __uint_as_float((unsigned)__builtin_amdgcn_update_dpp(u, u, CTRL, 0xF, 0xF, false));
}
static __device__ __forceinline__ float swz_xor4(float v) {
    return f_u((unsigned)__builtin_amdgcn_ds_swizzle((int)u_f(v), 0x101F));
}

#define AB_GATE_PK(OPX)                                                 \
    _Pragma("unroll")                                                   \
    for (int r = 0; r < AMPS; ++r) {                                    \
        f2 o; o.x = OPX(s[r].x); o.y = OPX(s[r].y);                     \
        CPLX_AB(s[r], CA, s[r], CB, o)                                  \
    }

// Register-bit wire: s0' = a(.)s0 + b(.)s1 ; s1' = -conj(b)(.)s0 + conj(a)(.)s1
template <int ST>
static __device__ __forceinline__ void reg_gate_pk(f2 (&s)[AMPS], f2 CAg, f2 CBg) {
#pragma unroll
    for (int r0 = 0; r0 < AMPS; ++r0) {
        if (r0 & ST) continue;
        const int r1 = r0 | ST;
        const f2 s0 = s[r0], s1 = s[r1];
        f2 t0, t1;
        PK_MUL_RR(t0, CAg, s0); PK_FMA_I (t0, CAg, s0);
        PK_FMA_R (t0, CBg, s1); PK_FMA_I (t0, CBg, s1);
        PK_MUL_RR(t1, CAg, s1); PK_FMA_IC(t1, CAg, s1);
        PK_FMA_RN(t1, CBg, s0); PK_FMA_I (t1, CBg, s0);
        s[r0] = t0; s[r1] = t1;
    }
}

// ---- fused U = RZ*RY*RX coefficient math ----
static __device__ __forceinline__ float4 build_coef(float alpha, float beta, float gamma) {
    float sa, ca, sb, cb, sg, cg;
    sincosf(0.5f * alpha, &sa, &ca);
    sincosf(0.5f * beta,  &sb, &cb);
    sincosf(0.5f * gamma, &sg, &cg);
    float cbca = cb * ca, sbsa = sb * sa, sbca = sb * ca, cbsa = cb * sa;
    float ar =  cg * cbca + sg * sbsa;
    float ai =  cg * sbsa - sg * cbca;
    float br = -(cg * sbca + sg * cbsa);
    float bi =  sg * sbca - cg * cbsa;
    return make_float4(ar, ai, br, bi);
}

// column-0 entry of U for a given wire bit: bit ? (-br, bi) : (ar, ai)
static __device__ __forceinline__ f2 usel(float4 c, int bit) {
    return bit ? f2{ -c.z, c.w } : f2{ c.x, c.y };
}

__global__ __launch_bounds__(256) void qsim_kernel(
    const float* __restrict__ x,
    const float* __restrict__ iscale,
    const float* __restrict__ w,
    const float* __restrict__ oscale,
    float* __restrict__ out)
{
    const int tid  = threadIdx.x;
    const int lane = tid & 63;
    const int wv   = tid >> 6;
    const int b    = blockIdx.x;

    __shared__ float4 buf[1536];    // 24 KB transpose buffer
    __shared__ float4 clds[CPB];    // 2.88 KB coef table

#define TBUF(SLOT, Q) buf[((((SLOT) << 1) | (Q)) << 6) | lane]

    // ---- prologue: all 180 fused gate matrices into LDS ----
    if (tid < CPB) {
        const int it  = tid / NQ;
        const int q   = tid - it * NQ;
        const int blk = it - 3 * (it / 3);
        float f     = x[(size_t)b * (4 * NQ) + NQ + blk * NQ + q];
        float alpha = iscale[it * NQ + q] * f;
        clds[tid] = build_coef(alpha, w[it * 2 * NQ + q], w[it * 2 * NQ + NQ + q]);
    }

    // CZ-ring sign masks for BOTH layouts
    unsigned czmA = 0, czmB = 0;
#pragma unroll
    for (int r = 0; r < AMPS; ++r) {
        unsigned ia = ((unsigned)wv << 10) | ((unsigned)lane << 4) | (unsigned)r;
        unsigned ib = (((unsigned)(r >> 3) & 1u) << 11) | (((unsigned)(r >> 2) & 1u) << 10)
                    | ((unsigned)lane << 4)
                    | (((unsigned)(wv >> 1) & 1u) << 3) | (((unsigned)wv & 1u) << 2)
                    | ((unsigned)r & 3u);
        unsigned pa = ((unsigned)__popc((ia & (ia >> 1)) & 0x7FFu) + ((ia & (ia >> 11)) & 1u)) & 1u;
        unsigned pb = ((unsigned)__popc((ib & (ib >> 1)) & 0x7FFu) + ((ib & (ib >> 11)) & 1u)) & 1u;
        czmA |= pa << r;
        czmB |= pb << r;
    }

    // lane-wire per-thread constants (bits 9..4 = wires 2..7 in BOTH layouts)
    const bool hb2 = (lane >> 5) & 1;
    const bool hb3 = (lane >> 4) & 1;
    const unsigned sb4 = (unsigned)((lane >> 3) & 1) << 31;
    const unsigned sb5 = (unsigned)((lane >> 2) & 1) << 31;
    const unsigned sb6 = (unsigned)((lane >> 1) & 1) << 31;
    const unsigned sb7 = (unsigned)(lane & 1) << 31;

    __syncthreads();   // coef table ready (also protects first buf writes)

    f2 s[AMPS];

    // ================= iteration 0: product-state fast path =================
    // amp(idx) = prod_q U_q[bit_q, 0];  U[0,0] = (ar,ai), U[1,0] = (-br, bi).
    // Built directly in layout B; CZ with czmB.
    {
        float4 c[NQ];
#pragma unroll
        for (int q = 0; q < NQ; ++q) c[q] = clds[q];

        // thread-constant product: wires 2..7 (lane bits 5..0), 8,9 (wv bits)
        f2 tc = usel(c[2], (lane >> 5) & 1);
#pragma unroll
        for (int wq = 3; wq <= 7; ++wq) {
            const f2 uw = usel(c[wq], (lane >> (7 - wq)) & 1);
            f2 t; CMUL(t, tc, uw) tc = t;
        }
        { f2 u = usel(c[8], (wv >> 1) & 1); f2 t; CMUL(t, tc, u) tc = t; }
        { f2 u = usel(c[9], wv & 1);        f2 t; CMUL(t, tc, u) tc = t; }

        // ph[j]: wires 0,1 by j=r>>2 (r3 -> wire0, r2 -> wire1), tc folded in
        // pl[k]: wires 10,11 by k=r&3 (r1 -> wire10, r0 -> wire11)
        f2 ph[4], pl[4];
#pragma unroll
        for (int j = 0; j < 4; ++j) {
            f2 u0 = usel(c[0], j >> 1), u1 = usel(c[1], j & 1);
            CMUL(ph[j], u0, u1)
            f2 t; CMUL(t, tc, ph[j]) ph[j] = t;
            f2 uA = usel(c[10], j >> 1), uB = usel(c[11], j & 1);
            CMUL(pl[j], uA, uB)
        }
#pragma unroll
        for (int r = 0; r < AMPS; ++r) CMUL(s[r], ph[r >> 2], pl[r & 3])

        // CZ ring in layout B
#pragma unroll
        for (int r = 0; r < AMPS; ++r) {
            const unsigned sgn = ((czmB >> r) & 1u) << 31;
            s[r].x = f_u(u_f(s[r].x) ^ sgn);
            s[r].y = f_u(u_f(s[r].y) ^ sgn);
        }
    }

    // ================= iterations 1..14 =================
#pragma unroll 2
    for (int it = 1; it < NIT; ++it) {
        float4 c[NQ];
#pragma unroll
        for (int q = 0; q < NQ; ++q) c[q] = clds[it * NQ + q];
        const bool ev = (it & 1) == 0;   // even iters enter layout A

        // ---- pre-transpose register wires ----
        // even (layout A): r3,r2 = wires 8,9 ; odd (layout B): r3,r2 = wires 0,1
        // wires 10,11 are r1,r0 in BOTH layouts
        {
            const float4 c0 = ev ? c[8] : c[0];
            const float4 c1 = ev ? c[9] : c[1];
            { const f2 CA = { c0.x, c0.y }, CB = { c0.z, c0.w }; reg_gate_pk<8>(s, CA, CB); }
            { const f2 CA = { c1.x, c1.y }, CB = { c1.z, c1.w }; reg_gate_pk<4>(s, CA, CB); }
            { const f2 CA = { c[10].x, c[10].y }, CB = { c[10].z, c[10].w }; reg_gate_pk<2>(s, CA, CB); }
            { const f2 CA = { c[11].x, c[11].y }, CB = { c[11].z, c[11].w }; reg_gate_pk<1>(s, CA, CB); }
        }

        // ---- lane wires (qubits 2..7), identical in both layouts ----
        { // qubit 2: xor32 -> permlane32_swap
            const f2 CP = { hb2 ? -c[2].z : c[2].x, hb2 ?  c[2].w : c[2].y };
            const f2 CQ = { hb2 ?  c[2].x : c[2].z, hb2 ? -c[2].y : c[2].w };
#pragma unroll
            for (int r = 0; r < AMPS; ++r) {
                auto dx = __builtin_amdgcn_permlane32_swap(u_f(s[r].x), u_f(s[r].x), false, false);
                auto dy = __builtin_amdgcn_permlane32_swap(u_f(s[r].y), u_f(s[r].y), false, false);
                f2 na = { f_u(dx[0]), f_u(dy[0]) };
                f2 nb = { f_u(dx[1]), f_u(dy[1]) };
                CPLX_AB(s[r], CP, na, CQ, nb)
            }
        }
        { // qubit 3: xor16 -> permlane16_swap
            const f2 CP = { hb3 ? -c[3].z : c[3].x, hb3 ?  c[3].w : c[3].y };
            const f2 CQ = { hb3 ?  c[3].x : c[3].z, hb3 ? -c[3].y : c[3].w };
#pragma unroll
            for (int r = 0; r < AMPS; ++r) {
                auto dx = __builtin_amdgcn_permlane16_swap(u_f(s[r].x), u_f(s[r].x), false, false);
                auto dy = __builtin_amdgcn_permlane16_swap(u_f(s[r].y), u_f(s[r].y), false, false);
                f2 na = { f_u(dx[0]), f_u(dy[0]) };
                f2 nb = { f_u(dx[1]), f_u(dy[1]) };
                CPLX_AB(s[r], CP, na, CQ, nb)
            }
        }
        { // qubit 4: xor8 -> DPP row_ror:8
            const f2 CA = { c[4].x, f_u(u_f(c[4].y) ^ sb4) };
            const f2 CB = { f_u(u_f(c[4].z) ^ sb4), c[4].w };
            AB_GATE_PK(dpp_xor<0x128>)
        }
        { // qubit 5: xor4 -> ds_swizzle; issue all gathers, then consume
            const f2 CA = { c[5].x, f_u(u_f(c[5].y) ^ sb5) };
            const f2 CB = { f_u(u_f(c[5].z) ^ sb5), c[5].w };
            float ox[AMPS], oy[AMPS];
#pragma unroll
            for (int r = 0; r < AMPS; ++r) {
                ox[r] = swz_xor4(s[r].x);
                oy[r] = swz_xor4(s[r].y);
            }
#pragma unroll
            for (int r = 0; r < AMPS; ++r) {
                f2 o = { ox[r], oy[r] };
                CPLX_AB(s[r], CA, s[r], CB, o)
            }
        }
        { // qubit 6: xor2 -> DPP quad_perm [2,3,0,1]
            const f2 CA = { c[6].x, f_u(u_f(c[6].y) ^ sb6) };
            const f2 CB = { f_u(u_f(c[6].z) ^ sb6), c[6].w };
            AB_GATE_PK(dpp_xor<0x4E>)
        }
        { // qubit 7: xor1 -> DPP quad_perm [1,0,3,2]
            const f2 CA = { c[7].x, f_u(u_f(c[7].y) ^ sb7) };
            const f2 CB = { f_u(u_f(c[7].z) ^ sb7), c[7].w };
            AB_GATE_PK(dpp_xor<0xB1>)
        }

        // ---- bit-transpose: swap contents of bits (11,10) <-> (3,2) ----
        // Safety: all threads passed the "buf consumed" barrier (end of the
        // PREVIOUS read phase) before these writes — no barrier needed here.
#pragma unroll
        for (int g = 0; g < 4; ++g) {
            if (g == wv) continue;                       // wave-uniform branch
            const int slot = g * 3 + (wv < g ? wv : wv - 1);
            TBUF(slot, 0) = make_float4(s[4*g+0].x, s[4*g+0].y, s[4*g+1].x, s[4*g+1].y);
            TBUF(slot, 1) = make_float4(s[4*g+2].x, s[4*g+2].y, s[4*g+3].x, s[4*g+3].y);
        }
        __syncthreads();   // writes visible to partners
#pragma unroll
        for (int h = 0; h < 4; ++h) {
            if (h == wv) continue;
            const int slot = wv * 3 + (h < wv ? h : h - 1);
            const float4 pa = TBUF(slot, 0);
            const float4 pb = TBUF(slot, 1);
            s[4*h+0] = f2{ pa.x, pa.y }; s[4*h+1] = f2{ pa.z, pa.w };
            s[4*h+2] = f2{ pb.x, pb.y }; s[4*h+3] = f2{ pb.z, pb.w };
        }
        __syncthreads();   // buf consumed — next iteration's writes are safe;
                           // skew absorbed by the ~3000-cycle gate stretch below

        // ---- post-transpose register wires ----
        // even (now layout B): r3,r2 = wires 0,1 ; odd (now layout A): wires 8,9
        {
            const float4 c0 = ev ? c[0] : c[8];
            const float4 c1 = ev ? c[1] : c[9];
            { const f2 CA = { c0.x, c0.y }, CB = { c0.z, c0.w }; reg_gate_pk<8>(s, CA, CB); }
            { const f2 CA = { c1.x, c1.y }, CB = { c1.z, c1.w }; reg_gate_pk<4>(s, CA, CB); }
        }

        // ---- CZ ring (diagonal +-1), mask per current layout ----
        const unsigned mcz = ev ? czmB : czmA;
#pragma unroll
        for (int r = 0; r < AMPS; ++r) {
            const unsigned sgn = ((mcz >> r) & 1u) << 31;
            s[r].x = f_u(u_f(s[r].x) ^ sgn);
            s[r].y = f_u(u_f(s[r].y) ^ sgn);
        }
    }

    // ---- expvals. Final layout: B (it=14 enters A, exits B).
    // wire0 = b11 = r3, wire1 = b10 = r2, wire2 = b9 = lane5, wire3 = b8 = lane4.
    float pg[4];
#pragma unroll
    for (int g = 0; g < 4; ++g) {
        float p = 0.f;
#pragma unroll
        for (int j = 0; j < 4; ++j)
            p = fmaf(s[4*g+j].x, s[4*g+j].x, fmaf(s[4*g+j].y, s[4*g+j].y, p));
        pg[g] = p;
    }
    const float ptot = (pg[0] + pg[1]) + (pg[2] + pg[3]);
    float v0 = (pg[0] + pg[1]) - (pg[2] + pg[3]);   // sign by r3
    float v1 = (pg[0] + pg[2]) - (pg[1] + pg[3]);   // sign by r2
    float v2 = hb2 ? -ptot : ptot;                  // lane5
    float v3 = hb3 ? -ptot : ptot;                  // lane4
#pragma unroll
    for (int m = 1; m <= 32; m <<= 1) {
        v0 += __shfl_xor(v0, m);
        v1 += __shfl_xor(v1, m);
        v2 += __shfl_xor(v2, m);
        v3 += __shfl_xor(v3, m);
    }

    // buf reuse for cross-wave reduction: all threads already passed the
    // loop's final "buf consumed" barrier, so lane-0 writes are safe.
    if (lane == 0) buf[wv] = make_float4(v0, v1, v2, v3);
    __syncthreads();
    if (tid == 0) {
        float4 a0 = buf[0], a1 = buf[1], a2 = buf[2], a3 = buf[3];
        float4 o;
        o.x = (a0.x + a1.x + a2.x + a3.x) * oscale[0];
        o.y = (a0.y + a1.y + a2.y + a3.y) * oscale[1];
        o.z = (a0.z + a1.z + a2.z + a3.z) * oscale[2];
        o.w = (a0.w + a1.w + a2.w + a3.w) * oscale[3];
        *reinterpret_cast<float4*>(out + (size_t)b * 4) = o;
    }
#undef TBUF
}

extern "C" void kernel_launch(void* const* d_in, const int* in_sizes, int n_in,
                              void* d_out, int out_size, void* d_ws, size_t ws_size,
                              hipStream_t stream) {
    const float* x      = (const float*)d_in[0];
    const float* iscale = (const float*)d_in[1];
    const float* w      = (const float*)d_in[2];
    const float* oscale = (const float*)d_in[3];
    float* out          = (float*)d_out;

    const int batch = in_sizes[0] / (4 * NQ);
    qsim_kernel<<<batch, 256, 0, stream>>>(x, iscale, w, oscale, out);
}